// Round 9
// baseline (78.379 us; speedup 1.0000x reference)
//
#include <hip/hip_runtime.h>
#include <hip/hip_bf16.h>
#include <math.h>

#define HID   128
#define TPB   256      // 4 waves per block, 64 rows per wave -> 256 rows per block-tile
#define TROWS 256
#define NBLK  512      // persistent grid (2 blocks/CU)

typedef __attribute__((ext_vector_type(8))) short        short8v;   // 8 bf16
typedef __attribute__((ext_vector_type(4))) float        f32x4;
typedef __attribute__((ext_vector_type(4))) unsigned int uint4v;

#define MFMA(a, b, c) __builtin_amdgcn_mfma_f32_16x16x32_bf16((a), (b), (c), 0, 0, 0)
#define SCHED_FENCE() __builtin_amdgcn_sched_barrier(0)

__device__ __forceinline__ unsigned int pk2bf(float lo, float hi) {
    unsigned short a = __builtin_bit_cast(unsigned short, __float2bfloat16(lo));
    unsigned short b = __builtin_bit_cast(unsigned short, __float2bfloat16(hi));
    return (unsigned int)a | ((unsigned int)b << 16);
}
__device__ __forceinline__ f32x4 relu4(f32x4 v) {
    f32x4 r;
    r.x = fmaxf(v.x, 0.f); r.y = fmaxf(v.y, 0.f);
    r.z = fmaxf(v.z, 0.f); r.w = fmaxf(v.w, 0.f);
    return r;
}

// 2 waves/EU -> 256-reg unified budget: 128 AGPR (layer-2 acc) + ~120 VGPR peak.
__global__ __launch_bounds__(TPB, 2)
void stress_kernel(const float* __restrict__ F,
                   const float* __restrict__ W1, const float* __restrict__ b1,
                   const float* __restrict__ W2, const float* __restrict__ b2,
                   const float* __restrict__ W3, const float* __restrict__ b3,
                   float* __restrict__ out, int N)
{
    // ---- LDS (38.5 KB -> 2 blocks/CU) ----
    __shared__ uint4v sA2[2048];   // W2^T A-frags: [(jt*4+ks)*64 + lane]
    __shared__ uint4v sA3[256];    // W3^T A-frags: [ks2*64 + lane]
    __shared__ __align__(16) float sW1[3 * HID];
    __shared__ __align__(16) float sb1[HID];
    __shared__ __align__(16) float sb2[HID];

    const int tid  = threadIdx.x;
    const int lane = tid & 63;
    const int wid  = tid >> 6;
    const int g    = lane >> 4;     // lane group 0..3
    const int lr   = lane & 15;

    // ---- one-time per-block weight staging / swizzling ----
    for (int e = tid; e < 2048; e += TPB) {
        int l = e & 63, ks = (e >> 6) & 3, jt = e >> 8;
        int k0 = 8 * (l >> 4) + 32 * ks;
        int j  = (l & 15) + 16 * jt;
        uint4v v;
        v.x = pk2bf(W2[(k0 + 0) * HID + j], W2[(k0 + 1) * HID + j]);
        v.y = pk2bf(W2[(k0 + 2) * HID + j], W2[(k0 + 3) * HID + j]);
        v.z = pk2bf(W2[(k0 + 4) * HID + j], W2[(k0 + 5) * HID + j]);
        v.w = pk2bf(W2[(k0 + 6) * HID + j], W2[(k0 + 7) * HID + j]);
        sA2[e] = v;
    }
    for (int e = tid; e < 256; e += TPB) {
        int l = e & 63, ks2 = e >> 6;
        int gg = l >> 4, t = l & 15;
        float w0  = (t < 4) ? W3[(4 * gg + 0 + 16 * (2 * ks2 + 0)) * 4 + t] : 0.f;
        float w1_ = (t < 4) ? W3[(4 * gg + 1 + 16 * (2 * ks2 + 0)) * 4 + t] : 0.f;
        float w2_ = (t < 4) ? W3[(4 * gg + 2 + 16 * (2 * ks2 + 0)) * 4 + t] : 0.f;
        float w3_ = (t < 4) ? W3[(4 * gg + 3 + 16 * (2 * ks2 + 0)) * 4 + t] : 0.f;
        float w4  = (t < 4) ? W3[(4 * gg + 0 + 16 * (2 * ks2 + 1)) * 4 + t] : 0.f;
        float w5  = (t < 4) ? W3[(4 * gg + 1 + 16 * (2 * ks2 + 1)) * 4 + t] : 0.f;
        float w6  = (t < 4) ? W3[(4 * gg + 2 + 16 * (2 * ks2 + 1)) * 4 + t] : 0.f;
        float w7  = (t < 4) ? W3[(4 * gg + 3 + 16 * (2 * ks2 + 1)) * 4 + t] : 0.f;
        uint4v v;
        v.x = pk2bf(w0, w1_); v.y = pk2bf(w2_, w3_);
        v.z = pk2bf(w4, w5);  v.w = pk2bf(w6, w7);
        sA3[e] = v;
    }
    for (int i = tid; i < 3 * HID; i += TPB) sW1[i] = W1[i];
    for (int i = tid; i < HID; i += TPB)     { sb1[i] = b1[i]; sb2[i] = b2[i]; }
    __syncthreads();

    const f32x4* pW1 = (const f32x4*)sW1;
    const f32x4* pB1 = (const f32x4*)sb1;
    const f32x4* pB2 = (const f32x4*)sb2;

    // persistent hoists: W3 frags (16 VGPR)
    const short8v a3f_0 = __builtin_bit_cast(short8v, sA3[0 * 64 + lane]);
    const short8v a3f_1 = __builtin_bit_cast(short8v, sA3[1 * 64 + lane]);
    const short8v a3f_2 = __builtin_bit_cast(short8v, sA3[2 * 64 + lane]);
    const short8v a3f_3 = __builtin_bit_cast(short8v, sA3[3 * 64 + lane]);

    const int nTiles = (N + TROWS - 1) / TROWS;
    const int tile0  = blockIdx.x;

    // prefetch F for the first tile (each lane owns one row)
    f32x4 fv = {0.f, 0.f, 0.f, 0.f};
    {
        const int n = tile0 * TROWS + wid * 64 + lane;
        if (tile0 < nTiles && n < N) fv = ((const f32x4*)F)[n];
    }

    for (int tile = tile0; tile < nTiles; tile += gridDim.x) {
        const int nbase = tile * TROWS + wid * 64;

        // ---- prologue (all 64 lanes): invariants + polar R for own row ----
        const float fa = fv.x, fb = fv.y, fc = fv.z, fd = fv.w;
        float x0, x1, x2, R00, R01, R10, R11;
        {
            const float J   = fa * fd - fb * fc;
            const float ss  = fa * fa + fb * fb + fc * fc + fd * fd;
            const float sgn = (J >= 0.f) ? 1.f : -1.f;
            const float r   = sqrtf(fmaxf(ss + 2.f * fabsf(J), 1e-30f));
            const float inv = 1.f / r;
            x0 = r - 2.f; x1 = ss - 1.f; x2 = J - 1.f;
            R00 = (fa + sgn * fd) * inv; R01 = (fb - sgn * fc) * inv;
            R10 = (fc - sgn * fb) * inv; R11 = (fd + sgn * fa) * inv;
        }
        // broadcast x per row-tile: x_RT_i = x_i of row RT*16+lr
        const float x_0_0 = __shfl(x0,      lr, 64), x_0_1 = __shfl(x1,      lr, 64), x_0_2 = __shfl(x2,      lr, 64);
        const float x_1_0 = __shfl(x0, 16 + lr, 64), x_1_1 = __shfl(x1, 16 + lr, 64), x_1_2 = __shfl(x2, 16 + lr, 64);
        const float x_2_0 = __shfl(x0, 32 + lr, 64), x_2_1 = __shfl(x1, 32 + lr, 64), x_2_2 = __shfl(x2, 32 + lr, 64);
        const float x_3_0 = __shfl(x0, 48 + lr, 64), x_3_1 = __shfl(x1, 48 + lr, 64), x_3_2 = __shfl(x2, 48 + lr, 64);
        SCHED_FENCE();

        // ---- layer-2 accumulators: 8 jt x 4 rt (128 regs, AGPR half) ----
        #define ACCDECL(JT) f32x4 acc_##JT##_0 = {0.f,0.f,0.f,0.f}, acc_##JT##_1 = {0.f,0.f,0.f,0.f}, \
                                  acc_##JT##_2 = {0.f,0.f,0.f,0.f}, acc_##JT##_3 = {0.f,0.f,0.f,0.f};
        ACCDECL(0) ACCDECL(1) ACCDECL(2) ACCDECL(3)
        ACCDECL(4) ACCDECL(5) ACCDECL(6) ACCDECL(7)
        #undef ACCDECL

        short8v bfr_0, bfr_1, bfr_2, bfr_3;

        #define HB(RT) {                                                              \
            const f32x4 hlo = relu4(blo + w0lo * x_##RT##_0 + w1lo * x_##RT##_1 + w2lo * x_##RT##_2); \
            const f32x4 hhi = relu4(bhi + w0hi * x_##RT##_0 + w1hi * x_##RT##_1 + w2hi * x_##RT##_2); \
            uint4v u;                                                                 \
            u.x = pk2bf(hlo.x, hlo.y); u.y = pk2bf(hlo.z, hlo.w);                     \
            u.z = pk2bf(hhi.x, hhi.y); u.w = pk2bf(hhi.z, hhi.w);                     \
            bfr_##RT = __builtin_bit_cast(short8v, u);                                \
        }
        #define STEP(JT, RT) acc_##JT##_##RT = MFMA(af_##JT, bfr_##RT, acc_##JT##_##RT)

        // ---- merged region per KS: {af reads | h-build VALU | MFMA} then fence.
        // ds_reads issue first, ~350cy of h-build covers their latency, MFMAs
        // consume; region boundary caps live ranges (spill-safe by construction).
        #define KSREGION(KS) {                                                        \
            const short8v af_0 = __builtin_bit_cast(short8v, sA2[(0*4+(KS))*64+lane]);\
            const short8v af_1 = __builtin_bit_cast(short8v, sA2[(1*4+(KS))*64+lane]);\
            const short8v af_2 = __builtin_bit_cast(short8v, sA2[(2*4+(KS))*64+lane]);\
            const short8v af_3 = __builtin_bit_cast(short8v, sA2[(3*4+(KS))*64+lane]);\
            const short8v af_4 = __builtin_bit_cast(short8v, sA2[(4*4+(KS))*64+lane]);\
            const short8v af_5 = __builtin_bit_cast(short8v, sA2[(5*4+(KS))*64+lane]);\
            const short8v af_6 = __builtin_bit_cast(short8v, sA2[(6*4+(KS))*64+lane]);\
            const short8v af_7 = __builtin_bit_cast(short8v, sA2[(7*4+(KS))*64+lane]);\
            const int q = 2 * g + 8 * (KS);                                           \
            const f32x4 w0lo = pW1[q],      w0hi = pW1[q + 1];                        \
            const f32x4 w1lo = pW1[32 + q], w1hi = pW1[32 + q + 1];                   \
            const f32x4 w2lo = pW1[64 + q], w2hi = pW1[64 + q + 1];                   \
            const f32x4 blo  = pB1[q],      bhi  = pB1[q + 1];                        \
            HB(0) HB(1) HB(2) HB(3)                                                   \
            __builtin_amdgcn_s_setprio(1);                                            \
            STEP(0,0); STEP(0,1); STEP(0,2); STEP(0,3);                               \
            STEP(1,0); STEP(1,1); STEP(1,2); STEP(1,3);                               \
            STEP(2,0); STEP(2,1); STEP(2,2); STEP(2,3);                               \
            STEP(3,0); STEP(3,1); STEP(3,2); STEP(3,3);                               \
            STEP(4,0); STEP(4,1); STEP(4,2); STEP(4,3);                               \
            STEP(5,0); STEP(5,1); STEP(5,2); STEP(5,3);                               \
            STEP(6,0); STEP(6,1); STEP(6,2); STEP(6,3);                               \
            STEP(7,0); STEP(7,1); STEP(7,2); STEP(7,3);                               \
            __builtin_amdgcn_s_setprio(0);                                            \
        } SCHED_FENCE();

        KSREGION(0)
        // next-tile F prefetch rides in its own tiny region right after KS0
        {
            const int tn = tile + gridDim.x;
            const int nn = tn * TROWS + wid * 64 + lane;
            fv = (f32x4){0.f, 0.f, 0.f, 0.f};
            if (tn < nTiles && nn < N) fv = ((const f32x4*)F)[nn];
        }
        KSREGION(1)
        KSREGION(2)
        KSREGION(3)
        #undef KSREGION
        #undef STEP
        #undef HB

        // ---- layer 3: one merged region (8 b2 reads up front, 16 MFMA) ----
        f32x4 accY_0 = {0.f,0.f,0.f,0.f}, accY_1 = {0.f,0.f,0.f,0.f},
              accY_2 = {0.f,0.f,0.f,0.f}, accY_3 = {0.f,0.f,0.f,0.f};
        {
            const f32x4 ba0 = pB2[g +  0], bb0 = pB2[g +  4];
            const f32x4 ba1 = pB2[g +  8], bb1 = pB2[g + 12];
            const f32x4 ba2 = pB2[g + 16], bb2 = pB2[g + 20];
            const f32x4 ba3 = pB2[g + 24], bb3 = pB2[g + 28];
            #define L3R(RT, JA, JB, KS2) {                                            \
                const f32x4 ha = relu4(acc_##JA##_##RT + ba##KS2);                    \
                const f32x4 hb = relu4(acc_##JB##_##RT + bb##KS2);                    \
                uint4v u;                                                             \
                u.x = pk2bf(ha.x, ha.y); u.y = pk2bf(ha.z, ha.w);                     \
                u.z = pk2bf(hb.x, hb.y); u.w = pk2bf(hb.z, hb.w);                     \
                accY_##RT = MFMA(a3f_##KS2, __builtin_bit_cast(short8v, u), accY_##RT); \
            }
            #define L3K(KS2, JA, JB) \
                L3R(0, JA, JB, KS2) L3R(1, JA, JB, KS2) L3R(2, JA, JB, KS2) L3R(3, JA, JB, KS2)
            L3K(0, 0, 1) L3K(1, 2, 3) L3K(2, 4, 5) L3K(3, 6, 7)
            #undef L3K
            #undef L3R
        }
        SCHED_FENCE();

        // ---- epilogue (one region): shfl F/R from owner lane, lanes 0..15 store ----
        #define EPI(RT, ACC) {                                                        \
            const float Ea  = __shfl(fa,  (RT)*16 + lr, 64);                          \
            const float Eb  = __shfl(fb,  (RT)*16 + lr, 64);                          \
            const float Ec  = __shfl(fc,  (RT)*16 + lr, 64);                          \
            const float Ed  = __shfl(fd,  (RT)*16 + lr, 64);                          \
            const float E00 = __shfl(R00, (RT)*16 + lr, 64);                          \
            const float E01 = __shfl(R01, (RT)*16 + lr, 64);                          \
            const float E10 = __shfl(R10, (RT)*16 + lr, 64);                          \
            const float E11 = __shfl(R11, (RT)*16 + lr, 64);                          \
            const int nn = nbase + (RT)*16 + lr;                                      \
            if (lane < 16 && nn < N) {                                                \
                const float y0 = ACC.x, y1 = ACC.y, y2 = ACC.z, y3 = ACC.w;           \
                const float s01 = 0.5f * (y1 + y2);                                   \
                const float P00 = E00 * y0  + E01 * s01;                              \
                const float P01 = E00 * s01 + E01 * y3;                               \
                const float P10 = E10 * y0  + E11 * s01;                              \
                const float P11 = E10 * s01 + E11 * y3;                               \
                f32x4 o;                                                              \
                o.x = P00 * Ea + P01 * Eb;                                            \
                o.y = P00 * Ec + P01 * Ed;                                            \
                o.z = P10 * Ea + P11 * Eb;                                            \
                o.w = P10 * Ec + P11 * Ed;                                            \
                ((f32x4*)out)[nn] = o;                                                \
            }                                                                         \
        }
        EPI(0, accY_0) EPI(1, accY_1) EPI(2, accY_2) EPI(3, accY_3)
        #undef EPI
        SCHED_FENCE();
    }
}

extern "C" void kernel_launch(void* const* d_in, const int* in_sizes, int n_in,
                              void* d_out, int out_size, void* d_ws, size_t ws_size,
                              hipStream_t stream) {
    const float* F  = (const float*)d_in[0];
    const float* W1 = (const float*)d_in[1];
    const float* b1 = (const float*)d_in[2];
    const float* W2 = (const float*)d_in[3];
    const float* b2 = (const float*)d_in[4];
    const float* W3 = (const float*)d_in[5];
    const float* b3 = (const float*)d_in[6];
    float* out = (float*)d_out;
    const int N = in_sizes[0] / 4;

    const int nTiles = (N + TROWS - 1) / TROWS;
    int grid = nTiles < NBLK ? nTiles : NBLK;
    stress_kernel<<<dim3(grid), dim3(TPB), 0, stream>>>(F, W1, b1, W2, b2, W3, b3, out, N);
}